// Round 1
// baseline (508.151 us; speedup 1.0000x reference)
//
#include <hip/hip_runtime.h>
#include <float.h>

#define N_PTS 262144
#define K_CL  1024
#define D     64
#define BN    128   // points per block
#define BK    128   // centroids per tile
#define NTILE (K_CL / BK)

// XOR swizzle: logical column `col` of LDS row `d` stored at col ^ (((d>>2)&7)<<2).
// Keeps 4-float groups contiguous (bits 0-1 untouched) and 16B aligned.
__device__ __forceinline__ int sw(int col, int d) {
    return col ^ (((d >> 2) & 7) << 2);
}

__global__ __launch_bounds__(256) void csq_kernel(const float* __restrict__ cent,
                                                  float* __restrict__ csq) {
    int k = blockIdx.x * 256 + threadIdx.x;
    if (k < K_CL) {
        float s = 0.f;
        #pragma unroll
        for (int d = 0; d < D; ++d) { float v = cent[k * D + d]; s = fmaf(v, v, s); }
        csq[k] = s;
    }
}

__global__ __launch_bounds__(256, 2) void kmeans_kernel(
    const float* __restrict__ batch,
    const float* __restrict__ cent,
    const float* __restrict__ csq,
    float* __restrict__ out_assign,   // [N] as float
    float* __restrict__ out_counts,   // [K] as float (atomicAdd)
    float* __restrict__ out_sums)     // [K][D] as float (atomicAdd)
{
    __shared__ float As[D][BN];   // 32 KB, transposed + swizzled: As[d][sw(p,d)] = x[p][d]
    __shared__ float Bs[D][BK];   // 32 KB, same layout for centroids

    const int tid = threadIdx.x;
    const int tx  = tid & 15;
    const int ty  = tid >> 4;
    const int p0  = ty * 8;               // this thread's 8 points (within tile)
    const int gp0 = blockIdx.x * BN;

    // ---- stage A tile (coalesced float4 loads, transpose into swizzled LDS)
    #pragma unroll
    for (int j = 0; j < 8; ++j) {
        int f  = tid + 256 * j;           // float4 index in [0,2048)
        int r  = f >> 4;                  // point row 0..127
        int c0 = (f & 15) << 2;           // dim 0..60
        float4 v = *reinterpret_cast<const float4*>(&batch[(size_t)(gp0 + r) * D + c0]);
        int colw = sw(r, c0);             // same mask for c0..c0+3
        As[c0 + 0][colw] = v.x;
        As[c0 + 1][colw] = v.y;
        As[c0 + 2][colw] = v.z;
        As[c0 + 3][colw] = v.w;
    }
    __syncthreads();

    // ---- ||x||^2 for this thread's 8 points (broadcast LDS reads, once per block)
    float xsq[8];
    #pragma unroll
    for (int i = 0; i < 8; ++i) {
        float s = 0.f;
        #pragma unroll
        for (int d = 0; d < D; ++d) {
            float v = As[d][sw(p0 + i, d)];
            s = fmaf(v, v, s);
        }
        xsq[i] = s;
    }

    float minv[8];
    int   mini[8];
    #pragma unroll
    for (int i = 0; i < 8; ++i) { minv[i] = FLT_MAX; mini[i] = 0; }

    for (int tile = 0; tile < NTILE; ++tile) {
        __syncthreads();                  // Bs reuse from previous tile
        #pragma unroll
        for (int j = 0; j < 8; ++j) {
            int f  = tid + 256 * j;
            int r  = f >> 4;
            int c0 = (f & 15) << 2;
            float4 v = *reinterpret_cast<const float4*>(&cent[(size_t)(tile * BK + r) * D + c0]);
            int colw = sw(r, c0);
            Bs[c0 + 0][colw] = v.x;
            Bs[c0 + 1][colw] = v.y;
            Bs[c0 + 2][colw] = v.z;
            Bs[c0 + 3][colw] = v.w;
        }
        __syncthreads();

        float dots[8][8];
        #pragma unroll
        for (int i = 0; i < 8; ++i)
            #pragma unroll
            for (int j = 0; j < 8; ++j) dots[i][j] = 0.f;

        #pragma unroll 4
        for (int k = 0; k < D; ++k) {
            int xm = ((k >> 2) & 7) << 2;
            float4 a0 = *reinterpret_cast<const float4*>(&As[k][(p0)     ^ xm]);
            float4 a1 = *reinterpret_cast<const float4*>(&As[k][(p0 + 4) ^ xm]);
            float4 b0 = *reinterpret_cast<const float4*>(&Bs[k][(tx * 8)     ^ xm]);
            float4 b1 = *reinterpret_cast<const float4*>(&Bs[k][(tx * 8 + 4) ^ xm]);
            float av[8] = {a0.x, a0.y, a0.z, a0.w, a1.x, a1.y, a1.z, a1.w};
            float bv[8] = {b0.x, b0.y, b0.z, b0.w, b1.x, b1.y, b1.z, b1.w};
            #pragma unroll
            for (int i = 0; i < 8; ++i)
                #pragma unroll
                for (int j = 0; j < 8; ++j)
                    dots[i][j] = fmaf(av[i], bv[j], dots[i][j]);
        }

        // epilogue: distances + running argmin (strict <, index tie-break = first occurrence)
        int cb = tile * BK + tx * 8;
        float4 c0v = *reinterpret_cast<const float4*>(&csq[cb]);
        float4 c1v = *reinterpret_cast<const float4*>(&csq[cb + 4]);
        float cs[8] = {c0v.x, c0v.y, c0v.z, c0v.w, c1v.x, c1v.y, c1v.z, c1v.w};
        #pragma unroll
        for (int i = 0; i < 8; ++i) {
            #pragma unroll
            for (int j = 0; j < 8; ++j) {
                float dist = (xsq[i] - 2.0f * dots[i][j]) + cs[j];
                int idx = cb + j;
                if (dist < minv[i] || (dist == minv[i] && idx < mini[i])) {
                    minv[i] = dist; mini[i] = idx;
                }
            }
        }
    }

    // ---- cross-thread argmin reduction (alias reduction buffers onto Bs; Bs is dead now)
    __syncthreads();
    float (*red_v)[16] = reinterpret_cast<float(*)[16]>(&Bs[0][0]);                         // 8 KB
    int   (*red_i)[16] = reinterpret_cast<int  (*)[16]>(reinterpret_cast<char*>(&Bs[0][0]) + 8192);
    int   *a_lds       = reinterpret_cast<int*>(reinterpret_cast<char*>(&Bs[0][0]) + 16384);

    #pragma unroll
    for (int i = 0; i < 8; ++i) {
        red_v[p0 + i][tx] = minv[i];
        red_i[p0 + i][tx] = mini[i];
    }
    __syncthreads();

    if (tid < BN) {
        int p = tid;
        float bv = red_v[p][0]; int bi = red_i[p][0];
        #pragma unroll
        for (int t = 1; t < 16; ++t) {
            float v = red_v[p][t]; int ii = red_i[p][t];
            if (v < bv || (v == bv && ii < bi)) { bv = v; bi = ii; }
        }
        a_lds[p] = bi;
        out_assign[gp0 + p] = (float)bi;
        atomicAdd(&out_counts[bi], 1.0f);
    }
    __syncthreads();

    // ---- scatter per-cluster sums: lane d covers dim d, wave covers one point per iter
    const int d = tid & 63;
    #pragma unroll 4
    for (int it = 0; it < 32; ++it) {
        int p = (tid >> 6) + (it << 2);   // 0..127
        int a = a_lds[p];
        float v = As[d][sw(p, d)];
        atomicAdd(&out_sums[(size_t)a * D + d], v);
    }
}

extern "C" void kernel_launch(void* const* d_in, const int* in_sizes, int n_in,
                              void* d_out, int out_size, void* d_ws, size_t ws_size,
                              hipStream_t stream) {
    const float* batch = (const float*)d_in[0];
    const float* cent  = (const float*)d_in[1];
    float* out        = (float*)d_out;
    float* out_assign = out;
    float* out_counts = out + N_PTS;
    float* out_sums   = out + N_PTS + K_CL;
    float* csq        = (float*)d_ws;

    // zero counts + sums region (assignments fully overwritten, no need)
    hipMemsetAsync(out_counts, 0, (size_t)(K_CL + K_CL * D) * sizeof(float), stream);
    csq_kernel<<<K_CL / 256, 256, 0, stream>>>(cent, csq);
    kmeans_kernel<<<N_PTS / BN, 256, 0, stream>>>(batch, cent, csq,
                                                  out_assign, out_counts, out_sums);
}

// Round 2
// 420.321 us; speedup vs baseline: 1.2090x; 1.2090x over previous
//
#include <hip/hip_runtime.h>
#include <float.h>

#define N_PTS 262144
#define K_CL  1024
#define D     64
#define BN    128   // points per block
#define BK    128   // centroids per tile
#define NTILE (K_CL / BK)
#define MARGIN_S 0.5f   // score margin = 0.5 -> distance margin 1.0 (fp16 err <= ~0.08)

typedef _Float16 f16;
typedef _Float16 half8 __attribute__((ext_vector_type(8)));
typedef float    f32x4 __attribute__((ext_vector_type(4)));

// ---- prep: csq (fp32, round-1 arithmetic), csqh = 0.5*csq, cent16 = fp16 pre-swizzled
// swizzle: phys 16B-chunk pc of row k holds logical chunk pc ^ (k&7)
__global__ __launch_bounds__(256) void prep_kernel(const float* __restrict__ cent,
                                                   float* __restrict__ csq,
                                                   float* __restrict__ csqh,
                                                   f16* __restrict__ cent16) {
    int k = blockIdx.x * 256 + threadIdx.x;
    if (k >= K_CL) return;
    const float* row = &cent[(size_t)k * D];
    float s = 0.f;
    #pragma unroll
    for (int d = 0; d < D; ++d) s = fmaf(row[d], row[d], s);
    csq[k]  = s;
    csqh[k] = 0.5f * s;
    int sw = k & 7;
    #pragma unroll
    for (int lch = 0; lch < 8; ++lch) {
        half8 h;
        #pragma unroll
        for (int e = 0; e < 8; ++e) h[e] = (f16)row[lch * 8 + e];
        *reinterpret_cast<half8*>(&cent16[(size_t)k * D + (size_t)((lch ^ sw) * 8)]) = h;
    }
}

// exact fp32 distance, replicating round-1's accepted arithmetic exactly
__device__ __forceinline__ float exact_dist(const float* __restrict__ xr,
                                            const float* __restrict__ cr,
                                            float xsq, float cs) {
    float dot = 0.f;
    #pragma unroll
    for (int d = 0; d < D; ++d) dot = fmaf(xr[d], cr[d], dot);
    return (xsq - 2.0f * dot) + cs;
}

__device__ __forceinline__ half8 frag_rd(const f16* base, int row, int ch) {
    // logical chunk ch of row -> phys chunk ch ^ (row&7)  (8 halves = 16 B)
    return *reinterpret_cast<const half8*>(&base[row * D + ((ch ^ (row & 7)) * 8)]);
}

__global__ __launch_bounds__(256, 3) void assign_kernel(
    const float* __restrict__ batch,
    const f16*   __restrict__ cent16,
    const float* __restrict__ csq,
    const float* __restrict__ csqh,
    const float* __restrict__ cent,
    float* __restrict__ out_assign,
    float* __restrict__ out_counts,
    float* __restrict__ out_sums)
{
    __shared__ f16 P16[BN * D];                    // 16 KB points (swizzled phys)
    __shared__ f16 C16[BK * D];                    // 16 KB centroid tile
    __shared__ __align__(16) float csqh_s[BK];     // 512 B
    __shared__ int a_lds[BN];

    const int tid  = threadIdx.x;
    const int wave = tid >> 6;
    const int lane = tid & 63;
    const int lo   = lane & 15;
    const int hi   = lane >> 4;
    const int gp0  = blockIdx.x * BN;

    // ---- stage P16 once: fp32 global -> fp16 swizzled LDS (coalesced 32B/lane)
    #pragma unroll
    for (int it = 0; it < 4; ++it) {
        int u = tid + 256 * it;            // (p, lch)
        int p = u >> 3, lch = u & 7;
        const float* src = &batch[(size_t)(gp0 + p) * D + lch * 8];
        half8 h;
        #pragma unroll
        for (int e = 0; e < 8; ++e) h[e] = (f16)src[e];
        *reinterpret_cast<half8*>(&P16[p * D + ((lch ^ (p & 7)) * 8)]) = h;
    }

    const int prow0 = wave * 32 + lo;          // point row, n=0
    const int prow1 = wave * 32 + 16 + lo;     // point row, n=1

    float m0 = -FLT_MAX, m1 = -FLT_MAX;

    // =================== PASS 1: per-lane approx max score ===================
    for (int tile = 0; tile < NTILE; ++tile) {
        __syncthreads();
        #pragma unroll
        for (int it = 0; it < 4; ++it) {
            int u = tid + 256 * it;
            *reinterpret_cast<half8*>(&C16[u * 8]) =
                *reinterpret_cast<const half8*>(&cent16[(size_t)tile * BK * D + (size_t)u * 8]);
        }
        if (tid < BK) csqh_s[tid] = csqh[tile * BK + tid];
        __syncthreads();

        f32x4 acc[8][2];
        #pragma unroll
        for (int m = 0; m < 8; ++m) {
            acc[m][0] = f32x4{0.f, 0.f, 0.f, 0.f};
            acc[m][1] = f32x4{0.f, 0.f, 0.f, 0.f};
        }
        #pragma unroll
        for (int ks = 0; ks < 2; ++ks) {
            half8 pf0 = frag_rd(P16, prow0, ks * 4 + hi);
            half8 pf1 = frag_rd(P16, prow1, ks * 4 + hi);
            #pragma unroll
            for (int m = 0; m < 8; ++m) {
                half8 cf = frag_rd(C16, m * 16 + lo, ks * 4 + hi);
                acc[m][0] = __builtin_amdgcn_mfma_f32_16x16x32_f16(cf, pf0, acc[m][0], 0, 0, 0);
                acc[m][1] = __builtin_amdgcn_mfma_f32_16x16x32_f16(cf, pf1, acc[m][1], 0, 0, 0);
            }
        }
        #pragma unroll
        for (int m = 0; m < 8; ++m) {
            f32x4 ch4 = *reinterpret_cast<const f32x4*>(&csqh_s[m * 16 + hi * 4]);
            f32x4 s0 = acc[m][0] - ch4;
            f32x4 s1 = acc[m][1] - ch4;
            m0 = fmaxf(m0, fmaxf(fmaxf(s0.x, s0.y), fmaxf(s0.z, s0.w)));
            m1 = fmaxf(m1, fmaxf(fmaxf(s1.x, s1.y), fmaxf(s1.z, s1.w)));
        }
    }

    // cross-lane max over the 4 hi-groups holding the same point
    m0 = fmaxf(m0, __shfl_xor(m0, 16)); m0 = fmaxf(m0, __shfl_xor(m0, 32));
    m1 = fmaxf(m1, __shfl_xor(m1, 16)); m1 = fmaxf(m1, __shfl_xor(m1, 32));
    const float thr0 = m0 - MARGIN_S, thr1 = m1 - MARGIN_S;

    int cnt0 = 0, cnt1 = 0;
    int la0 = 0, la1 = 0, la2 = 0, la3 = 0;
    int lb0 = 0, lb1 = 0, lb2 = 0, lb3 = 0;

    // =================== PASS 2: collect candidates within margin ===================
    for (int tile = 0; tile < NTILE; ++tile) {
        __syncthreads();
        #pragma unroll
        for (int it = 0; it < 4; ++it) {
            int u = tid + 256 * it;
            *reinterpret_cast<half8*>(&C16[u * 8]) =
                *reinterpret_cast<const half8*>(&cent16[(size_t)tile * BK * D + (size_t)u * 8]);
        }
        if (tid < BK) csqh_s[tid] = csqh[tile * BK + tid];
        __syncthreads();

        f32x4 acc[8][2];
        #pragma unroll
        for (int m = 0; m < 8; ++m) {
            acc[m][0] = f32x4{0.f, 0.f, 0.f, 0.f};
            acc[m][1] = f32x4{0.f, 0.f, 0.f, 0.f};
        }
        #pragma unroll
        for (int ks = 0; ks < 2; ++ks) {
            half8 pf0 = frag_rd(P16, prow0, ks * 4 + hi);
            half8 pf1 = frag_rd(P16, prow1, ks * 4 + hi);
            #pragma unroll
            for (int m = 0; m < 8; ++m) {
                half8 cf = frag_rd(C16, m * 16 + lo, ks * 4 + hi);
                acc[m][0] = __builtin_amdgcn_mfma_f32_16x16x32_f16(cf, pf0, acc[m][0], 0, 0, 0);
                acc[m][1] = __builtin_amdgcn_mfma_f32_16x16x32_f16(cf, pf1, acc[m][1], 0, 0, 0);
            }
        }
        #pragma unroll
        for (int m = 0; m < 8; ++m) {
            f32x4 ch4 = *reinterpret_cast<const f32x4*>(&csqh_s[m * 16 + hi * 4]);
            f32x4 s0 = acc[m][0] - ch4;
            f32x4 s1 = acc[m][1] - ch4;
            int cbase = tile * BK + m * 16 + hi * 4;
            float mx0 = fmaxf(fmaxf(s0.x, s0.y), fmaxf(s0.z, s0.w));
            if (mx0 >= thr0) {
                #pragma unroll
                for (int r = 0; r < 4; ++r) {
                    float sv = (r == 0) ? s0.x : (r == 1) ? s0.y : (r == 2) ? s0.z : s0.w;
                    if (sv >= thr0) {
                        if      (cnt0 == 0) la0 = cbase + r;
                        else if (cnt0 == 1) la1 = cbase + r;
                        else if (cnt0 == 2) la2 = cbase + r;
                        else if (cnt0 == 3) la3 = cbase + r;
                        cnt0++;
                    }
                }
            }
            float mx1 = fmaxf(fmaxf(s1.x, s1.y), fmaxf(s1.z, s1.w));
            if (mx1 >= thr1) {
                #pragma unroll
                for (int r = 0; r < 4; ++r) {
                    float sv = (r == 0) ? s1.x : (r == 1) ? s1.y : (r == 2) ? s1.z : s1.w;
                    if (sv >= thr1) {
                        if      (cnt1 == 0) lb0 = cbase + r;
                        else if (cnt1 == 1) lb1 = cbase + r;
                        else if (cnt1 == 2) lb2 = cbase + r;
                        else if (cnt1 == 3) lb3 = cbase + r;
                        cnt1++;
                    }
                }
            }
        }
    }

    // =================== exact fp32 resolve (round-1 arithmetic) ===================
    float bd0 = FLT_MAX, bd1 = FLT_MAX;
    int   bi0 = 0x7fffffff, bi1 = 0x7fffffff;

    if (cnt0 > 0) {
        const float* xr = &batch[(size_t)(gp0 + prow0) * D];
        float xsq = 0.f;
        #pragma unroll
        for (int d = 0; d < D; ++d) xsq = fmaf(xr[d], xr[d], xsq);
        if (cnt0 <= 4) {
            #pragma unroll
            for (int r = 0; r < 4; ++r) {
                int c = (r == 0) ? la0 : (r == 1) ? la1 : (r == 2) ? la2 : la3;
                if (r < cnt0) {
                    float dd = exact_dist(xr, &cent[(size_t)c * D], xsq, csq[c]);
                    if (dd < bd0 || (dd == bd0 && c < bi0)) { bd0 = dd; bi0 = c; }
                }
            }
        } else {  // overflow: exact scan of this lane's row slice (rows == hi*4..hi*4+3 mod 16)
            for (int t16 = 0; t16 < 64; ++t16) {
                #pragma unroll
                for (int r = 0; r < 4; ++r) {
                    int c = t16 * 16 + hi * 4 + r;
                    float dd = exact_dist(xr, &cent[(size_t)c * D], xsq, csq[c]);
                    if (dd < bd0 || (dd == bd0 && c < bi0)) { bd0 = dd; bi0 = c; }
                }
            }
        }
    }
    if (cnt1 > 0) {
        const float* xr = &batch[(size_t)(gp0 + prow1) * D];
        float xsq = 0.f;
        #pragma unroll
        for (int d = 0; d < D; ++d) xsq = fmaf(xr[d], xr[d], xsq);
        if (cnt1 <= 4) {
            #pragma unroll
            for (int r = 0; r < 4; ++r) {
                int c = (r == 0) ? lb0 : (r == 1) ? lb1 : (r == 2) ? lb2 : lb3;
                if (r < cnt1) {
                    float dd = exact_dist(xr, &cent[(size_t)c * D], xsq, csq[c]);
                    if (dd < bd1 || (dd == bd1 && c < bi1)) { bd1 = dd; bi1 = c; }
                }
            }
        } else {
            for (int t16 = 0; t16 < 64; ++t16) {
                #pragma unroll
                for (int r = 0; r < 4; ++r) {
                    int c = t16 * 16 + hi * 4 + r;
                    float dd = exact_dist(xr, &cent[(size_t)c * D], xsq, csq[c]);
                    if (dd < bd1 || (dd == bd1 && c < bi1)) { bd1 = dd; bi1 = c; }
                }
            }
        }
    }

    // cross-lane (hi-group) min reduce with first-index tie-break
    #pragma unroll
    for (int off = 16; off <= 32; off <<= 1) {
        float od = __shfl_xor(bd0, off); int oi = __shfl_xor(bi0, off);
        if (od < bd0 || (od == bd0 && oi < bi0)) { bd0 = od; bi0 = oi; }
        float oe = __shfl_xor(bd1, off); int oj = __shfl_xor(bi1, off);
        if (oe < bd1 || (oe == bd1 && oj < bi1)) { bd1 = oe; bi1 = oj; }
    }

    if (hi == 0) {
        a_lds[prow0] = bi0;
        out_assign[gp0 + prow0] = (float)bi0;
        atomicAdd(&out_counts[bi0], 1.0f);
        a_lds[prow1] = bi1;
        out_assign[gp0 + prow1] = (float)bi1;
        atomicAdd(&out_counts[bi1], 1.0f);
    }
    __syncthreads();

    // ---- scatter per-cluster sums: lane d covers dim d, wave covers one point/iter
    const int d = tid & 63;
    #pragma unroll 4
    for (int it = 0; it < 32; ++it) {
        int p = (tid >> 6) + (it << 2);
        int a = a_lds[p];
        float v = batch[(size_t)(gp0 + p) * D + d];
        atomicAdd(&out_sums[(size_t)a * D + d], v);
    }
}

extern "C" void kernel_launch(void* const* d_in, const int* in_sizes, int n_in,
                              void* d_out, int out_size, void* d_ws, size_t ws_size,
                              hipStream_t stream) {
    const float* batch = (const float*)d_in[0];
    const float* cent  = (const float*)d_in[1];
    float* out        = (float*)d_out;
    float* out_assign = out;
    float* out_counts = out + N_PTS;
    float* out_sums   = out + N_PTS + K_CL;

    float* csq    = (float*)d_ws;                                 // 1024 f32
    float* csqh   = csq + K_CL;                                   // 1024 f32
    f16*   cent16 = (f16*)((char*)d_ws + 8192);                   // 128 KB fp16, pre-swizzled

    hipMemsetAsync(out_counts, 0, (size_t)(K_CL + K_CL * D) * sizeof(float), stream);
    prep_kernel<<<K_CL / 256, 256, 0, stream>>>(cent, csq, csqh, cent16);
    assign_kernel<<<N_PTS / BN, 256, 0, stream>>>(batch, cent16, csq, csqh, cent,
                                                  out_assign, out_counts, out_sums);
}